// Round 1
// 102.313 us; speedup vs baseline: 1.0029x; 1.0029x over previous
//
#include <hip/hip_runtime.h>

// Causal attention head. B=4, T=4096, C=384, H=16. fp32 in/out.
// Round 7: VALU-trim of flash_v5 (theory: at 32 waves/CU the kernel is
// VALU-issue-bound on exp/cvt/store per-element work, not MFMA or memory):
//  - swapped QK^T: sf = mfma(K, Q) -> C[key][q]. A/B fragment addressing is
//    identical (lane&15 indexes both A-rows and B-cols), so K/Q loads are
//    byte-identical; only C layout flips: lane holds 4 CONSECUTIVE keys per
//    quad for fixed q=col.
//  - v_cvt_pk_bf16_f32 packs P pairs (RNE, same as old manual f2bf): 8 instrs
//    vs ~48 VALU; P store becomes 4x ds_write_b64 (uint2) vs 16x ds_write_b16.
//  - l-reduce: 1 scalar + shfl_xor(16,32) vs 4 accs x 4 xor steps.
//  - qkv_mfma: x->bf16 A-pack via v_cvt_pk_bf16_f32 (saves ~170 VALU/wave).
// P LDS layout [q][key] stride 72, PV path, partial-write scheme unchanged.
// Fixed harness floor ~52us (256MB ws re-poison 44us + restores) on top.

constexpr int B_DIM = 4;
constexpr int T_SEQ = 4096;
constexpr int C_DIM = 384;
constexpr int H_DIM = 16;
constexpr int NROW  = B_DIM * T_SEQ; // 16384

typedef __bf16 bf16x8 __attribute__((ext_vector_type(8)));
typedef float  f32x4  __attribute__((ext_vector_type(4)));

__device__ __forceinline__ unsigned short f2bf(float f) {
  unsigned int u = __builtin_bit_cast(unsigned int, f);
  u += 0x7fffu + ((u >> 16) & 1u);   // RNE (finite inputs)
  return (unsigned short)(u >> 16);
}
__device__ __forceinline__ bf16x8 as_bf16x8(uint4 u) {
  return __builtin_bit_cast(bf16x8, u);
}
__device__ __forceinline__ unsigned cvt_pk_bf16(float lo, float hi) {
  unsigned r;
  asm("v_cvt_pk_bf16_f32 %0, %1, %2" : "=v"(r) : "v"(lo), "v"(hi));
  return r;
}

// ---------------------------------------------------------------------------
// Kernel 0: W -> WT bf16, layout [m][n=16][k=384]. 18432 elements.
// ---------------------------------------------------------------------------
__global__ __launch_bounds__(256) void wconv(
    const float* __restrict__ Wk, const float* __restrict__ Wq,
    const float* __restrict__ Wv, unsigned short* __restrict__ WT) {
  const int i = blockIdx.x * 256 + threadIdx.x;   // grid 72*256 = 18432
  const int m = i / 6144;
  const int r = i - m * 6144;
  const int n = r / 384;
  const int k = r - n * 384;
  const float* __restrict__ W = (m == 0) ? Wk : (m == 1) ? Wq : Wv;
  WT[i] = f2bf(W[k * 16 + n]);
}

// ---------------------------------------------------------------------------
// Kernel 1: QKV projection via MFMA, 2-way K-split.
// ---------------------------------------------------------------------------
__global__ __launch_bounds__(128) void qkv_mfma(
    const float* __restrict__ x, const unsigned short* __restrict__ WT,
    unsigned short* __restrict__ Kb,   // [NROW][16]
    unsigned short* __restrict__ Qb,   // [NROW][32] scaled + zero-padded
    unsigned short* __restrict__ VTb)  // [B][16][T]
{
  const int tid  = threadIdx.x;
  const int w    = tid >> 6;           // 0..1
  const int lane = tid & 63;
  const int quad = lane >> 4;
  const int col  = lane & 15;
  const int r0   = blockIdx.x << 4;
  const int kb   = w * 6;              // this wave's kk base

  __shared__ float mrg[12][64];

  const float4* __restrict__ xp =
      reinterpret_cast<const float4*>(x + (size_t)(r0 + col) * C_DIM) + quad * 2;
  float4 araw[12];
#pragma unroll
  for (int kk = 0; kk < 6; ++kk) {
    araw[2 * kk]     = xp[(kb + kk) * 8];
    araw[2 * kk + 1] = xp[(kb + kk) * 8 + 1];
  }

  const uint4* __restrict__ bk = reinterpret_cast<const uint4*>(
      WT + (size_t)col * 384 + quad * 8);
  const uint4* __restrict__ bq = bk + 768;    // +6144 shorts
  const uint4* __restrict__ bv = bk + 1536;   // +12288 shorts

  f32x4 ck = {0.f, 0.f, 0.f, 0.f};
  f32x4 cq = {0.f, 0.f, 0.f, 0.f};
  f32x4 cv = {0.f, 0.f, 0.f, 0.f};
#pragma unroll
  for (int kk = 0; kk < 6; ++kk) {
    uint4 pk;
    const float4 a0 = araw[2 * kk], a1 = araw[2 * kk + 1];
    pk.x = cvt_pk_bf16(a0.x, a0.y);
    pk.y = cvt_pk_bf16(a0.z, a0.w);
    pk.z = cvt_pk_bf16(a1.x, a1.y);
    pk.w = cvt_pk_bf16(a1.z, a1.w);
    const bf16x8 av = as_bf16x8(pk);
    ck = __builtin_amdgcn_mfma_f32_16x16x32_bf16(av, as_bf16x8(bk[(kb + kk) * 4]), ck, 0, 0, 0);
    cq = __builtin_amdgcn_mfma_f32_16x16x32_bf16(av, as_bf16x8(bq[(kb + kk) * 4]), cq, 0, 0, 0);
    cv = __builtin_amdgcn_mfma_f32_16x16x32_bf16(av, as_bf16x8(bv[(kb + kk) * 4]), cv, 0, 0, 0);
  }

  if (w == 1) {
#pragma unroll
    for (int r = 0; r < 4; ++r) {
      mrg[r][lane]     = ck[r];
      mrg[4 + r][lane] = cq[r];
      mrg[8 + r][lane] = cv[r];
    }
  }
  __syncthreads();
  if (w == 0) {
    const float SC = 0.25f * 1.44269504088896341f;  // softmax scale * log2(e)
#pragma unroll
    for (int r = 0; r < 4; ++r) {
      const float vk = ck[r] + mrg[r][lane];
      const float vq = cq[r] + mrg[4 + r][lane];
      const float vv = cv[r] + mrg[8 + r][lane];
      const int row = r0 + quad * 4 + r;
      Kb[row * 16 + col]      = f2bf(vk);
      Qb[row * 32 + col]      = f2bf(vq * SC);
      Qb[row * 32 + 16 + col] = 0;
      const int bb = row >> 12, t = row & 4095;
      VTb[(((size_t)(bb * 16 + col)) << 12) + t] = f2bf(vv);
    }
  }
}

// ---------------------------------------------------------------------------
// Kernel 2: bf16 MFMA flash attention, key-split x2, per-wave global partials.
// grid 2048: blk = qtp*8 + b*2 + h (heavy qt first). slot = h*4 + w in [0,8).
// Wave handles chunks c = slot, slot+8, ... < nch. Writes (O,l) partial sums
// to PO[slot][row][16] / PL[slot][row]; idle waves write zeros.
// Swapped QK^T -> C[key][q]; packed cvt + b64 P stores. No barriers at all.
// ---------------------------------------------------------------------------
__global__ __launch_bounds__(256) void flash_v5(
    const unsigned short* __restrict__ Qb,
    const unsigned short* __restrict__ Kb,
    const unsigned short* __restrict__ VTb,
    float* __restrict__ PO, float* __restrict__ PL)
{
  const int tid  = threadIdx.x;
  const int w    = tid >> 6;
  const int lane = tid & 63;
  const int quad = lane >> 4;
  const int col  = lane & 15;
  const int qt   = 255 - (blockIdx.x >> 3);   // heavy first
  const int b    = (blockIdx.x >> 1) & 3;
  const int h    = blockIdx.x & 1;
  const int slot = h * 4 + w;                 // 0..7
  const int r0   = qt << 4;

  __shared__ __attribute__((aligned(16))) unsigned short Pl[4][2][16 * 72];

  const uint4* qp = reinterpret_cast<const uint4*>(
      Qb + (((size_t)(b * T_SEQ + r0 + col)) << 5) + quad * 8);
  const bf16x8 qa = as_bf16x8(qp[0]);

  f32x4 o = {0.f, 0.f, 0.f, 0.f};
  float l4[4] = {0.f, 0.f, 0.f, 0.f};

  const unsigned short* Kbase = Kb + ((size_t)(b * T_SEQ) << 4);
  const unsigned short* Vbase = VTb + (((size_t)(b * 16 + col)) << 12);
  const int nch = (qt + 4) >> 2;
  const int poff = col * 72 + quad * 4;       // P store offset (shorts)

  unsigned short* const P0 = Pl[w][0];
  unsigned short* const P1 = Pl[w][1];

  auto computeP = [&](int c, unsigned short* P) {
    const int kt0 = c << 2;
    f32x4 sf[4];
#pragma unroll
    for (int t = 0; t < 4; ++t) {
      const int kt = kt0 + t;
      if (kt <= qt) {
        const uint4* kp = reinterpret_cast<const uint4*>(
            Kbase + (((size_t)(kt * 16 + col)) << 4) + quad * 8);
        f32x4 z = {0.f, 0.f, 0.f, 0.f};
        // swapped: A = K tile (rows=keys), B = Q tile (cols=q). Same loads as
        // unswapped (A lane&15 = m, B lane&15 = n); C[key][q]:
        //   q = lane&15 = col, key = t*16 + quad*4 + r  (consecutive in r!)
        sf[t] = __builtin_amdgcn_mfma_f32_16x16x32_bf16(as_bf16x8(kp[0]), qa, z, 0, 0, 0);
      } else {
#pragma unroll
        for (int r = 0; r < 4; ++r) sf[t][r] = -1e30f;
      }
    }
    const int td = qt - kt0;
    if (td >= 0 && td < 4) {
#pragma unroll
      for (int r = 0; r < 4; ++r)
        if (quad * 4 + r > col) sf[td][r] = -1e30f;   // key > q
    }
#pragma unroll
    for (int t = 0; t < 4; ++t) {
      const float p0 = __builtin_amdgcn_exp2f(sf[t][0]);  // -1e30 -> 0
      const float p1 = __builtin_amdgcn_exp2f(sf[t][1]);
      const float p2 = __builtin_amdgcn_exp2f(sf[t][2]);
      const float p3 = __builtin_amdgcn_exp2f(sf[t][3]);
      l4[t] += (p0 + p1) + (p2 + p3);
      uint2 pr;
      pr.x = cvt_pk_bf16(p0, p1);   // RNE, bit-identical to old f2bf path
      pr.y = cvt_pk_bf16(p2, p3);
      *reinterpret_cast<uint2*>(P + poff + t * 16) = pr;  // ds_write_b64
    }
  };

  auto doPV = [&](int c, const unsigned short* P) {
    const uint4 v0 = *reinterpret_cast<const uint4*>(Vbase + c * 64 + quad * 8);
    const uint4 v1 = *reinterpret_cast<const uint4*>(Vbase + c * 64 + 32 + quad * 8);
    const uint4 p0 = *reinterpret_cast<const uint4*>(P + col * 72 + quad * 8);
    const uint4 p1 = *reinterpret_cast<const uint4*>(P + col * 72 + 32 + quad * 8);
    o = __builtin_amdgcn_mfma_f32_16x16x32_bf16(as_bf16x8(p0), as_bf16x8(v0), o, 0, 0, 0);
    o = __builtin_amdgcn_mfma_f32_16x16x32_bf16(as_bf16x8(p1), as_bf16x8(v1), o, 0, 0, 0);
  };

  int c = slot;
  if (c < nch) {
    computeP(c, P0);
    int last = c; c += 8;
    while (c < nch) {
      computeP(c, P1);
      doPV(last, P0);
      last = c; c += 8;
      if (c >= nch) { doPV(last, P1); last = -1; break; }
      computeP(c, P0);
      doPV(last, P1);
      last = c; c += 8;
    }
    if (last >= 0) doPV(last, P0);
  }

  // l is per-q (q = col); sum partials across the 4 quads sharing each col
  float l = (l4[0] + l4[1]) + (l4[2] + l4[3]);
  l += __shfl_xor(l, 16);
  l += __shfl_xor(l, 32);

  // write partials (zeros if this wave had no chunks)
  const size_t rowbase = (size_t)b * T_SEQ + r0;
  float* pO = PO + ((size_t)slot * NROW + rowbase) * 16;
#pragma unroll
  for (int r = 0; r < 4; ++r)
    pO[(quad * 4 + r) * 16 + col] = o[r];
  if (quad == 0) PL[(size_t)slot * NROW + rowbase + col] = l;
}

// ---------------------------------------------------------------------------
// Kernel 3: merge 8 partial slots: out = sum(O) / sum(l).
// ---------------------------------------------------------------------------
__global__ __launch_bounds__(256) void flash_merge(
    const float* __restrict__ PO, const float* __restrict__ PL,
    float* __restrict__ out)
{
  const int i   = blockIdx.x * 256 + threadIdx.x;   // grid 1024*256 = 262144
  const int row = i >> 4;
  float O = 0.f, L = 0.f;
#pragma unroll
  for (int s = 0; s < 8; ++s) {
    O += PO[((size_t)s * NROW) * 16 + i];
    L += PL[(size_t)s * NROW + row];
  }
  out[i] = O / L;
}

extern "C" void kernel_launch(void* const* d_in, const int* in_sizes, int n_in,
                              void* d_out, int out_size, void* d_ws, size_t ws_size,
                              hipStream_t stream) {
  const float* x  = (const float*)d_in[0];
  const float* Wk = (const float*)d_in[1];
  const float* Wq = (const float*)d_in[2];
  const float* Wv = (const float*)d_in[3];
  float* outp = (float*)d_out;

  // ws: Qb [NROW*32]sh | Kb [NROW*16]sh | 64 slack | VTb [NROW*16]sh |
  //     WT [18432]sh | PO [8*NROW*16]f32 | PL [8*NROW]f32   (~11 MB total)
  unsigned short* Qb  = (unsigned short*)d_ws;
  unsigned short* Kb  = Qb + (size_t)NROW * 32;
  unsigned short* VTb = Kb + (size_t)NROW * 16 + 64;
  unsigned short* WT  = VTb + (size_t)NROW * 16;
  float* PO = (float*)(WT + 18432);
  float* PL = PO + (size_t)8 * NROW * 16;

  wconv<<<72, 256, 0, stream>>>(Wk, Wq, Wv, WT);
  qkv_mfma<<<1024, 128, 0, stream>>>(x, WT, Kb, Qb, VTb);
  flash_v5<<<2048, 256, 0, stream>>>(Qb, Kb, VTb, PO, PL);
  flash_merge<<<1024, 256, 0, stream>>>(PO, PL, outp);
}